// Round 4
// baseline (38626.855 us; speedup 1.0000x reference)
//
#include <hip/hip_runtime.h>

#define HIDDEN  100
#define SEQLEN  65536
#define XTILE   256
#define NT      256   // 4 waves, one per SIMD

typedef float f32x2 __attribute__((ext_vector_type(2)));
typedef float f32x4 __attribute__((ext_vector_type(4)));

#define DPP_XOR1 0xB1  // quad_perm [1,0,3,2]: lane <-> lane^1

#if defined(__has_builtin) && __has_builtin(__builtin_amdgcn_rcpf)
#define RCPF(x) __builtin_amdgcn_rcpf(x)
#else
#define RCPF(x) (1.0f / (x))
#endif

#define QSWAP(v) __int_as_float(__builtin_amdgcn_mov_dpp(__float_as_int(v), DPP_XOR1, 0xf, 0xf, true))

static __device__ __forceinline__ f32x2 pkfma(f32x2 a, f32x2 b, f32x2 c) {
#if defined(__has_builtin) && __has_builtin(__builtin_elementwise_fma)
    return __builtin_elementwise_fma(a, b, c);   // -> v_pk_fma_f32
#else
    f32x2 r; r.x = __builtin_fmaf(a.x, b.x, c.x); r.y = __builtin_fmaf(a.y, b.y, c.y); return r;
#endif
}

// Thread pair (2j, 2j+1) owns hidden unit j:
//   even lane (p=0): rows j      (gate i) and 100+j (gate f)
//   odd  lane (p=1): rows 200+j  (gate g) and 300+j (gate o)
// After activations, one quad-DPP swap gives the even lane all 4 gates.
__global__ __launch_bounds__(NT) __attribute__((amdgpu_waves_per_eu(1, 1)))
void lstm_seq4(const float* __restrict__ x,      // [SEQ][4]
               const float* __restrict__ W_ih,   // [400][4]
               const float* __restrict__ W_hh,   // [400][100]
               const float* __restrict__ b_ih,   // [400]
               const float* __restrict__ b_hh,   // [400]
               const float* __restrict__ W_lin,  // [1][100]
               const float* __restrict__ b_lin,  // [1]
               float* __restrict__ out)          // [1]
{
    __shared__ __align__(16) float hbuf[2][112];  // double-buffered hidden state
    __shared__ __align__(16) f32x4 xs[XTILE];     // staged input tile
    __shared__ float red[112];

    const int tid = threadIdx.x;
    const int j   = tid >> 1;        // hidden unit 0..127 (active <100)
    const int p   = tid & 1;         // 0: (i,f)  1: (g,o)
    const bool active = (j < HIDDEN);

    const int rA = p ? (200 + j) : j;          // i or g row
    const int rB = p ? (300 + j) : (100 + j);  // f or o row

    // ---- two W_hh rows per lane in registers (200 floats; waves_per_eu(1,1) => full file) ----
    f32x4 wrA[25], wrB[25];
    f32x4 wihA = (f32x4)(0.f), wihB = (f32x4)(0.f);
    float biasA = 0.f, biasB = 0.f;
    if (active) {
        const f32x4* a4 = reinterpret_cast<const f32x4*>(W_hh + rA * HIDDEN);
        const f32x4* b4 = reinterpret_cast<const f32x4*>(W_hh + rB * HIDDEN);
#pragma unroll
        for (int q = 0; q < 25; ++q) { wrA[q] = a4[q]; wrB[q] = b4[q]; }
        wihA  = reinterpret_cast<const f32x4*>(W_ih)[rA];
        wihB  = reinterpret_cast<const f32x4*>(W_ih)[rB];
        biasA = b_ih[rA] + b_hh[rA];
        biasB = b_ih[rB] + b_hh[rB];
    }
    const float mA  = p ? 2.0f : 1.0f;   // tanh(s) = 2*sigmoid(2s)-1 for gate g
    const float mA1 = mA - 1.0f;
    float c = 0.f;                       // cell state lives in even lanes

    if (tid < 112) { hbuf[0][tid] = 0.f; hbuf[1][tid] = 0.f; }
    __syncthreads();

    // one barrier per step: read hr, write hw (other buffer), sync
    auto step = [&](const float* hr, float* hw, const f32x4 xv) {
        const f32x4* h4 = reinterpret_cast<const f32x4*>(hr);
        f32x2 a0, a1, b0, b1;
        a0.x = __builtin_fmaf(wihA.x, xv.x, biasA);  a0.y = wihA.y * xv.y;
        a1.x = wihA.z * xv.z;                        a1.y = wihA.w * xv.w;
        b0.x = __builtin_fmaf(wihB.x, xv.x, biasB);  b0.y = wihB.y * xv.y;
        b1.x = wihB.z * xv.z;                        b1.y = wihB.w * xv.w;
#pragma unroll
        for (int q = 0; q < 25; ++q) {
            f32x4 h = h4[q];                 // LDS broadcast read (b128)
            a0 = pkfma(wrA[q].xy, h.xy, a0);
            a1 = pkfma(wrA[q].zw, h.zw, a1);
            b0 = pkfma(wrB[q].xy, h.xy, b0);
            b1 = pkfma(wrB[q].zw, h.zw, b1);
        }
        f32x2 sa = a0 + a1;  float sA = sa.x + sa.y;   // row A preact (i or g)
        f32x2 sb = b0 + b1;  float sB = sb.x + sb.y;   // row B preact (f or o)

        // row A: sigmoid (p=0) or tanh via 2*sig(2s)-1 (p=1); row B: always sigmoid
        float uA   = sA * mA;
        float actA = __builtin_fmaf(mA, RCPF(1.0f + __expf(-uA)), -mA1);
        float actB = RCPF(1.0f + __expf(-sB));

        float gA = QSWAP(actA);   // partner's row-A act (g for even lanes)
        float gB = QSWAP(actB);   // partner's row-B act (o for even lanes)

        if (p == 0 && active) {
            // i=actA, f=actB, g=gA, o=gB
            c = __builtin_fmaf(actB, c, actA * gA);
            float th = __builtin_fmaf(-2.0f, RCPF(1.0f + __expf(2.0f * c)), 1.0f);
            hw[j] = gB * th;
        }
        __syncthreads();
    };

    const f32x4* x4 = reinterpret_cast<const f32x4*>(x);
    for (int t0 = 0; t0 < SEQLEN; t0 += XTILE) {
        xs[tid] = x4[t0 + tid];
        __syncthreads();
        for (int tt = 0; tt < XTILE; tt += 2) {
            step(hbuf[0], hbuf[1], xs[tt]);      // even: read buf0, write buf1
            step(hbuf[1], hbuf[0], xs[tt + 1]);  // odd:  read buf1, write buf0
        }
    }
    // after an even number of steps the current h is in hbuf[0]

    if (tid < HIDDEN) red[tid] = hbuf[0][tid] * W_lin[tid];
    __syncthreads();
    if (tid == 0) {
        float s = b_lin[0];
        for (int q = 0; q < HIDDEN; ++q) s += red[q];
        out[0] = s;
    }
}

extern "C" void kernel_launch(void* const* d_in, const int* in_sizes, int n_in,
                              void* d_out, int out_size, void* d_ws, size_t ws_size,
                              hipStream_t stream) {
    const float* x     = (const float*)d_in[0];
    const float* W_ih  = (const float*)d_in[1];
    const float* W_hh  = (const float*)d_in[2];
    const float* b_ih  = (const float*)d_in[3];
    const float* b_hh  = (const float*)d_in[4];
    const float* W_lin = (const float*)d_in[5];
    const float* b_lin = (const float*)d_in[6];
    float* out = (float*)d_out;

    lstm_seq4<<<dim3(1), dim3(NT), 0, stream>>>(
        x, W_ih, W_hh, b_ih, b_hh, W_lin, b_lin, out);
}

// Round 5
// 38105.676 us; speedup vs baseline: 1.0137x; 1.0137x over previous
//
#include <hip/hip_runtime.h>

#define HIDDEN  100
#define GATES   400
#define SEQLEN  65536
#define XTILE   256
#define NT      448   // 7 waves: 2/SIMD on three SIMDs, 1 on the fourth

typedef float f32x2 __attribute__((ext_vector_type(2)));
typedef float f32x4 __attribute__((ext_vector_type(4)));

// quad_perm DPP controls: lane <- lane^1 / ^2 within each 4-lane group
#define DPP_XOR1 0xB1  // [1,0,3,2]
#define DPP_XOR2 0x4E  // [2,3,0,1]

#if defined(__has_builtin) && __has_builtin(__builtin_amdgcn_rcpf)
#define RCPF(x) __builtin_amdgcn_rcpf(x)
#else
#define RCPF(x) (1.0f / (x))
#endif

#define QSWAP(v, ctrl) __int_as_float(__builtin_amdgcn_mov_dpp(__float_as_int(v), (ctrl), 0xf, 0xf, true))

static __device__ __forceinline__ f32x2 pkfma(f32x2 a, f32x2 b, f32x2 c) {
#if defined(__has_builtin) && __has_builtin(__builtin_elementwise_fma)
    return __builtin_elementwise_fma(a, b, c);   // -> v_pk_fma_f32
#else
    f32x2 r; r.x = __builtin_fmaf(a.x, b.x, c.x); r.y = __builtin_fmaf(a.y, b.y, c.y); return r;
#endif
}

__global__ __launch_bounds__(NT) __attribute__((amdgpu_waves_per_eu(2, 2)))
void lstm_seq5(const float* __restrict__ x,      // [SEQ][4]
               const float* __restrict__ W_ih,   // [400][4]
               const float* __restrict__ W_hh,   // [400][100]
               const float* __restrict__ b_ih,   // [400]
               const float* __restrict__ b_hh,   // [400]
               const float* __restrict__ W_lin,  // [1][100]
               const float* __restrict__ b_lin,  // [1]
               float* __restrict__ out)          // [1]
{
    __shared__ __align__(16) float hbuf[2][112];  // double-buffered hidden state
    __shared__ __align__(16) f32x4 xs[XTILE];     // staged input tile
    __shared__ float red[112];

    const int tid = threadIdx.x;
    const int j   = tid >> 2;       // h index 0..99 (quads 100..111 inactive)
    const int k   = tid & 3;        // gate type: 0=i 1=f 2=g 3=o
    const int r   = k * HIDDEN + (j < HIDDEN ? j : 0);
    const bool is_gate = (tid < GATES);

    // ---- per-thread W_hh row in registers ----
    f32x4 wr[25];
    f32x4 wih = (f32x4)(0.f);
    float bias = 0.f, m = 1.f, m1 = 0.f;
    if (is_gate) {
        const f32x4* wrow = reinterpret_cast<const f32x4*>(W_hh + r * HIDDEN);
#pragma unroll
        for (int q = 0; q < 25; ++q) wr[q] = wrow[q];
        wih  = reinterpret_cast<const f32x4*>(W_ih)[r];
        bias = b_ih[r] + b_hh[r];
        m  = (k == 2) ? 2.0f : 1.0f;  // tanh(s) = 2*sigmoid(2s)-1
        m1 = m - 1.0f;
    }
    float c = 0.f;                  // cell state lives in k==0 lanes

    if (tid < 112) { hbuf[0][tid] = 0.f; hbuf[1][tid] = 0.f; }
    __syncthreads();

    // one barrier per step; h PREFETCHED into registers before the FMA burst
    auto step = [&](const float* hr, float* hw, const f32x4 xv) {
        if (is_gate) {
            const f32x4* h4 = reinterpret_cast<const f32x4*>(hr);
            f32x4 ha[25];
#pragma unroll
            for (int q = 0; q < 25; ++q) ha[q] = h4[q];   // 25 back-to-back ds_read_b128

            f32x2 acc0, acc1, acc2, acc3;
            acc0.x = __builtin_fmaf(wih.x, xv.x, bias);
            acc0.y = wih.y * xv.y;
            acc1.x = wih.z * xv.z;
            acc1.y = wih.w * xv.w;
            acc2 = (f32x2)(0.f);
            acc3 = (f32x2)(0.f);
#pragma unroll
            for (int q = 0; q < 25; ++q) {                // pure-FMA burst
                if (q & 1) {
                    acc2 = pkfma(wr[q].xy, ha[q].xy, acc2);
                    acc3 = pkfma(wr[q].zw, ha[q].zw, acc3);
                } else {
                    acc0 = pkfma(wr[q].xy, ha[q].xy, acc0);
                    acc1 = pkfma(wr[q].zw, ha[q].zw, acc1);
                }
            }
            f32x2 sv = (acc0 + acc1) + (acc2 + acc3);
            float s  = sv.x + sv.y;
            // sigmoid for i,f,o (m=1); tanh via 2*sig(2s)-1 (m=2)
            float u   = s * m;
            float e   = __expf(-u);
            float a   = RCPF(1.0f + e);
            float act = __builtin_fmaf(m, a, -m1);
            // gather quad's 4 activations into lane k==0 (VALU DPP, no barrier)
            float g1 = QSWAP(act, DPP_XOR1);
            float g2 = QSWAP(act, DPP_XOR2);
            float g3 = QSWAP(g1,  DPP_XOR2);
            if (k == 0 && j < HIDDEN) {
                float ig = act, fg = g1, gg = g2, og = g3;
                c = __builtin_fmaf(fg, c, ig * gg);
                float e2 = __expf(2.0f * c);
                float th = __builtin_fmaf(-2.0f, RCPF(1.0f + e2), 1.0f); // tanh(c)
                hw[j] = og * th;
            }
        }
        __syncthreads();
    };

    const f32x4* x4 = reinterpret_cast<const f32x4*>(x);
    for (int t0 = 0; t0 < SEQLEN; t0 += XTILE) {
        if (tid < XTILE) xs[tid] = x4[t0 + tid];
        __syncthreads();
        for (int tt = 0; tt < XTILE; tt += 2) {
            step(hbuf[0], hbuf[1], xs[tt]);      // even: read buf0, write buf1
            step(hbuf[1], hbuf[0], xs[tt + 1]);  // odd:  read buf1, write buf0
        }
    }
    // after an even number of steps the current h is in hbuf[0]

    if (tid < HIDDEN) red[tid] = hbuf[0][tid] * W_lin[tid];
    __syncthreads();
    if (tid == 0) {
        float s = b_lin[0];
        for (int q = 0; q < HIDDEN; ++q) s += red[q];
        out[0] = s;
    }
}

extern "C" void kernel_launch(void* const* d_in, const int* in_sizes, int n_in,
                              void* d_out, int out_size, void* d_ws, size_t ws_size,
                              hipStream_t stream) {
    const float* x     = (const float*)d_in[0];
    const float* W_ih  = (const float*)d_in[1];
    const float* W_hh  = (const float*)d_in[2];
    const float* b_ih  = (const float*)d_in[3];
    const float* b_hh  = (const float*)d_in[4];
    const float* W_lin = (const float*)d_in[5];
    const float* b_lin = (const float*)d_in[6];
    float* out = (float*)d_out;

    lstm_seq5<<<dim3(1), dim3(NT), 0, stream>>>(
        x, W_ih, W_hh, b_ih, b_hh, W_lin, b_lin, out);
}

// Round 6
// 28192.868 us; speedup vs baseline: 1.3701x; 1.3516x over previous
//
#include <hip/hip_runtime.h>

#define HIDDEN  100
#define SEQLEN  65536
#define XTILE   256
#define NT      256   // 4 waves

typedef float    f32x4 __attribute__((ext_vector_type(4)));
typedef _Float16 h16x2 __attribute__((ext_vector_type(2)));

#define DPP_XOR1 0xB1  // quad_perm [1,0,3,2]: lane <-> lane^1
#define DPP_XOR2 0x4E  // quad_perm [2,3,0,1]: lane <-> lane^2

#if defined(__has_builtin) && __has_builtin(__builtin_amdgcn_rcpf)
#define RCPF(x) __builtin_amdgcn_rcpf(x)
#else
#define RCPF(x) (1.0f / (x))
#endif

#define QSWAP(v, ctrl) __int_as_float(__builtin_amdgcn_mov_dpp(__float_as_int(v), (ctrl), 0xf, 0xf, true))

static __device__ __forceinline__ h16x2 as_h2(unsigned u) {
    union { unsigned u; h16x2 h; } cv; cv.u = u; return cv.h;
}
static __device__ __forceinline__ unsigned as_u32(h16x2 h) {
    union { h16x2 h; unsigned u; } cv; cv.h = h; return cv.u;
}

// f32 acc += dot2(f16x2, f16x2): v_dot2_f32_f16 if available
static __device__ __forceinline__ float dot2(h16x2 a, h16x2 b, float c) {
#if defined(__has_builtin) && __has_builtin(__builtin_amdgcn_fdot2)
    return __builtin_amdgcn_fdot2(a, b, c, false);
#else
    return __builtin_fmaf((float)a.y, (float)b.y, __builtin_fmaf((float)a.x, (float)b.x, c));
#endif
}

// Thread pair (2j, 2j+1) owns hidden unit j (j = tid>>1):
//   even lane (p=0): rows j (gate i)     and 100+j (gate f)
//   odd  lane (p=1): rows 200+j (gate g) and 300+j (gate o)
// h stored in LDS as packed f16x2 (52 dwords incl. zero pad); weights f16x2 in VGPRs.
__global__ __launch_bounds__(NT) __attribute__((amdgpu_waves_per_eu(1, 1)))
void lstm_seq6(const float* __restrict__ x,      // [SEQ][4]
               const float* __restrict__ W_ih,   // [400][4]
               const float* __restrict__ W_hh,   // [400][100]
               const float* __restrict__ b_ih,   // [400]
               const float* __restrict__ b_hh,   // [400]
               const float* __restrict__ W_lin,  // [1][100]
               const float* __restrict__ b_lin,  // [1]
               float* __restrict__ out)          // [1]
{
    __shared__ __align__(16) unsigned hbuf[2][64]; // h as f16x2 pairs: 52 dwords used (100 h + 4 zero pad)
    __shared__ __align__(16) f32x4 xs[XTILE];      // staged input tile (f32)
    __shared__ float red[112];

    const int tid = threadIdx.x;
    const int j   = tid >> 1;        // hidden unit 0..127 (active <100)
    const int p   = tid & 1;         // 0: (i,f)  1: (g,o)
    const bool active = (j < HIDDEN);

    const int rA = p ? (200 + j) : j;          // i or g row
    const int rB = p ? (300 + j) : (100 + j);  // f or o row

    // ---- two W_hh rows per lane, packed f16x2: 52 dwords each (pad 100->104 with zeros) ----
    h16x2 wA[52], wB[52];
    f32x4 wihA = (f32x4)(0.f), wihB = (f32x4)(0.f);
    float biasA = 0.f, biasB = 0.f;
#pragma unroll
    for (int q = 0; q < 52; ++q) { wA[q] = (h16x2)(_Float16)0; wB[q] = (h16x2)(_Float16)0; }
    if (active) {
        const float* a = W_hh + rA * HIDDEN;
        const float* b = W_hh + rB * HIDDEN;
#pragma unroll
        for (int q = 0; q < 50; ++q) {
            h16x2 pa, pb;
            pa.x = (_Float16)a[2*q]; pa.y = (_Float16)a[2*q+1];
            pb.x = (_Float16)b[2*q]; pb.y = (_Float16)b[2*q+1];
            wA[q] = pa; wB[q] = pb;
        }
        wihA  = reinterpret_cast<const f32x4*>(W_ih)[rA];
        wihB  = reinterpret_cast<const f32x4*>(W_ih)[rB];
        biasA = b_ih[rA] + b_hh[rA];
        biasB = b_ih[rB] + b_hh[rB];
    }
    const float mA  = p ? 2.0f : 1.0f;   // tanh(s) = 2*sigmoid(2s)-1 for gate g
    const float mA1 = mA - 1.0f;
    float c = 0.f;                       // cell state: lives in p==0 lanes

    if (tid < 64) { hbuf[0][tid] = 0u; hbuf[1][tid] = 0u; }
    __syncthreads();

    // one barrier per step: read hr, write hw (other buffer), sync
    auto step = [&](const unsigned* hr, unsigned* hw, const f32x4 xv) {
        // x-part + bias in f32 (exact)
        float accA0 = __builtin_fmaf(wihA.x, xv.x, biasA);
        float accA1 = wihA.y * xv.y;
        accA0 = __builtin_fmaf(wihA.z, xv.z, accA0);
        accA1 = __builtin_fmaf(wihA.w, xv.w, accA1);
        float accB0 = __builtin_fmaf(wihB.x, xv.x, biasB);
        float accB1 = wihB.y * xv.y;
        accB0 = __builtin_fmaf(wihB.z, xv.z, accB0);
        accB1 = __builtin_fmaf(wihB.w, xv.w, accB1);

        const uint4* h4 = reinterpret_cast<const uint4*>(hr);
#pragma unroll
        for (int q = 0; q < 13; ++q) {           // 13 ds_read_b128, broadcast
            uint4 hv = h4[q];
            h16x2 h0 = as_h2(hv.x), h1 = as_h2(hv.y), h2 = as_h2(hv.z), h3 = as_h2(hv.w);
            accA0 = dot2(wA[4*q+0], h0, accA0);
            accA1 = dot2(wA[4*q+1], h1, accA1);
            accA0 = dot2(wA[4*q+2], h2, accA0);
            accA1 = dot2(wA[4*q+3], h3, accA1);
            accB0 = dot2(wB[4*q+0], h0, accB0);
            accB1 = dot2(wB[4*q+1], h1, accB1);
            accB0 = dot2(wB[4*q+2], h2, accB0);
            accB1 = dot2(wB[4*q+3], h3, accB1);
        }
        float sA = accA0 + accA1;   // i (p=0) or g (p=1) preact
        float sB = accB0 + accB1;   // f (p=0) or o (p=1) preact

        // row A: sigmoid (p=0) or tanh via 2*sig(2s)-1 (p=1); row B: sigmoid
        float uA   = sA * mA;
        float actA = __builtin_fmaf(mA, RCPF(1.0f + __expf(-uA)), -mA1);
        float actB = RCPF(1.0f + __expf(-sB));

        float gA = QSWAP(actA, DPP_XOR1);   // partner's row-A act (g for even lanes)
        float gB = QSWAP(actB, DPP_XOR1);   // partner's row-B act (o for even lanes)

        float hval = 0.f;
        if (p == 0) {
            // i=actA, f=actB, g=gA, o=gB
            c = __builtin_fmaf(actB, c, actA * gA);
            float th = __builtin_fmaf(-2.0f, RCPF(1.0f + __expf(2.0f * c)), 1.0f);
            hval = gB * th;                  // h[j], f32
        }
        // pack (h[2m], h[2m+1]) from lanes 4m / 4m+2 and write one dword
        float hpart = QSWAP(hval, DPP_XOR2);  // lane 4m gets lane 4m+2's h
        if ((tid & 3) == 0 && active) {
            h16x2 hp;
            hp.x = (_Float16)hval;            // unit 2m  (low half)
            hp.y = (_Float16)hpart;           // unit 2m+1 (high half)
            hw[tid >> 2] = as_u32(hp);
        }
        __syncthreads();
    };

    const f32x4* x4 = reinterpret_cast<const f32x4*>(x);
    for (int t0 = 0; t0 < SEQLEN; t0 += XTILE) {
        xs[tid] = x4[t0 + tid];
        __syncthreads();
        for (int tt = 0; tt < XTILE; tt += 2) {
            step(hbuf[0], hbuf[1], xs[tt]);      // even: read buf0, write buf1
            step(hbuf[1], hbuf[0], xs[tt + 1]);  // odd:  read buf1, write buf0
        }
    }
    // after an even number of steps the current h is in hbuf[0]

    if (tid < HIDDEN) {
        h16x2 hp = as_h2(hbuf[0][tid >> 1]);
        float hj = (tid & 1) ? (float)hp.y : (float)hp.x;
        red[tid] = hj * W_lin[tid];
    }
    __syncthreads();
    if (tid == 0) {
        float s = b_lin[0];
        for (int q = 0; q < HIDDEN; ++q) s += red[q];
        out[0] = s;
    }
}

extern "C" void kernel_launch(void* const* d_in, const int* in_sizes, int n_in,
                              void* d_out, int out_size, void* d_ws, size_t ws_size,
                              hipStream_t stream) {
    const float* x     = (const float*)d_in[0];
    const float* W_ih  = (const float*)d_in[1];
    const float* W_hh  = (const float*)d_in[2];
    const float* b_ih  = (const float*)d_in[3];
    const float* b_hh  = (const float*)d_in[4];
    const float* W_lin = (const float*)d_in[5];
    const float* b_lin = (const float*)d_in[6];
    float* out = (float*)d_out;

    lstm_seq6<<<dim3(1), dim3(NT), 0, stream>>>(
        x, W_ih, W_hh, b_ih, b_hh, W_lin, b_lin, out);
}

// Round 8
// 26694.449 us; speedup vs baseline: 1.4470x; 1.0561x over previous
//
#include <hip/hip_runtime.h>

#define HIDDEN  100
#define SEQLEN  65536
#define XTILE   256
#define NT      256   // 4 waves, one per SIMD

typedef float    f32x4 __attribute__((ext_vector_type(4)));
typedef _Float16 h16x2 __attribute__((ext_vector_type(2)));

#define DPP_XOR1 0xB1  // quad_perm [1,0,3,2]: lane <-> lane^1
#define DPP_XOR2 0x4E  // quad_perm [2,3,0,1]: lane <-> lane^2

#if defined(__has_builtin) && __has_builtin(__builtin_amdgcn_rcpf)
#define RCPF(x) __builtin_amdgcn_rcpf(x)
#else
#define RCPF(x) (1.0f / (x))
#endif

#define QSWAP(v, ctrl) __int_as_float(__builtin_amdgcn_mov_dpp(__float_as_int(v), (ctrl), 0xf, 0xf, true))

static __device__ __forceinline__ h16x2 as_h2(unsigned u) {
    union { unsigned u; h16x2 h; } cv; cv.u = u; return cv.h;
}
static __device__ __forceinline__ unsigned pack_f16(float a, float b) {
#if defined(__has_builtin) && __has_builtin(__builtin_amdgcn_cvt_pkrtz)
    auto v = __builtin_amdgcn_cvt_pkrtz(a, b);          // __fp16 ext_vector(2)
    union { decltype(v) h; unsigned u; } cv; cv.h = v;  // bit-cast, no conversion
    return cv.u;
#else
    union { h16x2 h; unsigned u; } cv;
    cv.h.x = (_Float16)a; cv.h.y = (_Float16)b;
    return cv.u;
#endif
}
static __device__ __forceinline__ float dot2(h16x2 a, h16x2 b, float c) {
#if defined(__has_builtin) && __has_builtin(__builtin_amdgcn_fdot2)
    return __builtin_amdgcn_fdot2(a, b, c, false);
#else
    return __builtin_fmaf((float)a.y, (float)b.y, __builtin_fmaf((float)a.x, (float)b.x, c));
#endif
}

// Lane pair (2j, 2j+1) owns hidden unit j. Each lane computes HALF the K-sum
// (even: k 0..49, odd: k 50..99) for ALL FOUR gate rows {j,100+j,200+j,300+j};
// one DPP-XOR1 add merges halves, then both lanes run the uniform cell update.
// h lives in LDS as f16, padded layout: slots 0..49 = units 0..49, 50..55 = 0,
// slots 56..105 = units 50..99, 106..111 = 0  (so each half is 28 aligned dwords).
__global__ __launch_bounds__(NT) __attribute__((amdgpu_waves_per_eu(1, 1)))
void lstm_seq7(const float* __restrict__ x,      // [SEQ][4]
               const float* __restrict__ W_ih,   // [400][4]
               const float* __restrict__ W_hh,   // [400][100]
               const float* __restrict__ b_ih,   // [400]
               const float* __restrict__ b_hh,   // [400]
               const float* __restrict__ W_lin,  // [1][100]
               const float* __restrict__ b_lin,  // [1]
               float* __restrict__ out)          // [1]
{
    __shared__ __align__(16) unsigned hbuf[2][64]; // 56 dwords used (112 f16 slots)
    __shared__ __align__(16) f32x4 xs[XTILE];      // staged input tile (f32)
    __shared__ float red[112];

    const int tid = threadIdx.x;
    const int j   = tid >> 1;        // hidden unit (active < 100)
    const int p   = tid & 1;         // K-half: 0 -> k<50, 1 -> k>=50
    const bool active = (j < HIDDEN);
    const int jj  = active ? j : 0;
    const int off = p * 50;          // K offset for this lane

    // ---- per-lane weights: 4 gate half-rows, packed f16x2 (28 dwords each, zero-padded) ----
    h16x2 w[4][28];
    float wx0[4], wx1[4], bz[4];     // x-part seeds (even lane also carries bias)
#pragma unroll
    for (int g = 0; g < 4; ++g) {
        const int row = g * HIDDEN + jj;
        const float* wr = W_hh + row * HIDDEN + off;
#pragma unroll
        for (int q = 0; q < 25; ++q) {
            h16x2 pw; pw.x = (_Float16)wr[2*q]; pw.y = (_Float16)wr[2*q+1];
            w[g][q] = pw;
        }
#pragma unroll
        for (int q = 25; q < 28; ++q) w[g][q] = (h16x2)(_Float16)0;
        const f32x4 wih = reinterpret_cast<const f32x4*>(W_ih)[row];
        wx0[g] = p ? wih.z : wih.x;
        wx1[g] = p ? wih.w : wih.y;
        bz[g]  = p ? 0.f : (b_ih[row] + b_hh[row]);
    }
    float c = 0.f;                   // cell state (redundant in both lanes of pair)

    if (tid < 64) { hbuf[0][tid] = 0u; hbuf[1][tid] = 0u; }
    __syncthreads();

    // one barrier per step: read hr (my half), write hw (other buffer), sync
    auto step = [&](const unsigned* hr, unsigned* hw, const f32x4 xv) {
        const uint4* h4 = reinterpret_cast<const uint4*>(hr + (p ? 28 : 0));
        uint4 hv[7];
#pragma unroll
        for (int t = 0; t < 7; ++t) hv[t] = h4[t];   // 7 ds_read_b128, issued up-front

        const float xe0 = p ? xv.z : xv.x;
        const float xe1 = p ? xv.w : xv.y;
        float a0 = __builtin_fmaf(wx1[0], xe1, __builtin_fmaf(wx0[0], xe0, bz[0]));
        float a1 = __builtin_fmaf(wx1[1], xe1, __builtin_fmaf(wx0[1], xe0, bz[1]));
        float a2 = __builtin_fmaf(wx1[2], xe1, __builtin_fmaf(wx0[2], xe0, bz[2]));
        float a3 = __builtin_fmaf(wx1[3], xe1, __builtin_fmaf(wx0[3], xe0, bz[3]));
#pragma unroll
        for (int t = 0; t < 7; ++t) {
            const h16x2 h0 = as_h2(hv[t].x), h1 = as_h2(hv[t].y);
            const h16x2 h2 = as_h2(hv[t].z), h3 = as_h2(hv[t].w);
            a0 = dot2(w[0][4*t+0], h0, a0); a1 = dot2(w[1][4*t+0], h0, a1);
            a2 = dot2(w[2][4*t+0], h0, a2); a3 = dot2(w[3][4*t+0], h0, a3);
            a0 = dot2(w[0][4*t+1], h1, a0); a1 = dot2(w[1][4*t+1], h1, a1);
            a2 = dot2(w[2][4*t+1], h1, a2); a3 = dot2(w[3][4*t+1], h1, a3);
            a0 = dot2(w[0][4*t+2], h2, a0); a1 = dot2(w[1][4*t+2], h2, a1);
            a2 = dot2(w[2][4*t+2], h2, a2); a3 = dot2(w[3][4*t+2], h2, a3);
            a0 = dot2(w[0][4*t+3], h3, a0); a1 = dot2(w[1][4*t+3], h3, a1);
            a2 = dot2(w[2][4*t+3], h3, a2); a3 = dot2(w[3][4*t+3], h3, a3);
        }
        // merge K-halves across the lane pair (both lanes end with full sums)
        a0 += QSWAP(a0, DPP_XOR1);
        a1 += QSWAP(a1, DPP_XOR1);
        a2 += QSWAP(a2, DPP_XOR1);
        a3 += QSWAP(a3, DPP_XOR1);

        const float i_ = RCPF(1.0f + __expf(-a0));
        const float f_ = RCPF(1.0f + __expf(-a1));
        const float g_ = __builtin_fmaf(-2.0f, RCPF(1.0f + __expf(2.0f * a2)), 1.0f);
        const float o_ = RCPF(1.0f + __expf(-a3));
        c = __builtin_fmaf(f_, c, i_ * g_);
        const float th   = __builtin_fmaf(-2.0f, RCPF(1.0f + __expf(2.0f * c)), 1.0f);
        const float hval = o_ * th;

        // pack h pair (units 2m, 2m+1) in lane 4m and store one dword
        const float hoth = QSWAP(hval, DPP_XOR2);  // lane 4m <- lane 4m+2's h
        if ((tid & 3) == 0 && active) {
            const int m  = tid >> 2;               // pair index, 0..49
            const int dw = (m < 25) ? m : m + 3;   // padded-slot dword
            hw[dw] = pack_f16(hval, hoth);
        }
        __syncthreads();
    };

    const f32x4* x4 = reinterpret_cast<const f32x4*>(x);
    for (int t0 = 0; t0 < SEQLEN; t0 += XTILE) {
        xs[tid] = x4[t0 + tid];
        __syncthreads();
        for (int tt = 0; tt < XTILE; tt += 2) {
            step(hbuf[0], hbuf[1], xs[tt]);      // even: read buf0, write buf1
            step(hbuf[1], hbuf[0], xs[tt + 1]);  // odd:  read buf1, write buf0
        }
    }
    // after an even number of steps the current h is in hbuf[0]

    if (tid < HIDDEN) {
        const int slot = (tid < 50) ? tid : tid + 6;
        const h16x2 hp = as_h2(hbuf[0][slot >> 1]);
        const float hj = (slot & 1) ? (float)hp.y : (float)hp.x;
        red[tid] = hj * W_lin[tid];
    }
    __syncthreads();
    if (tid == 0) {
        float s = b_lin[0];
        for (int q = 0; q < HIDDEN; ++q) s += red[q];
        out[0] = s;
    }
}

extern "C" void kernel_launch(void* const* d_in, const int* in_sizes, int n_in,
                              void* d_out, int out_size, void* d_ws, size_t ws_size,
                              hipStream_t stream) {
    const float* x     = (const float*)d_in[0];
    const float* W_ih  = (const float*)d_in[1];
    const float* W_hh  = (const float*)d_in[2];
    const float* b_ih  = (const float*)d_in[3];
    const float* b_hh  = (const float*)d_in[4];
    const float* W_lin = (const float*)d_in[5];
    const float* b_lin = (const float*)d_in[6];
    float* out = (float*)d_out;

    lstm_seq7<<<dim3(1), dim3(NT), 0, stream>>>(
        x, W_ih, W_hh, b_ih, b_hh, W_lin, b_lin, out);
}

// Round 9
// 24854.353 us; speedup vs baseline: 1.5541x; 1.0740x over previous
//
#include <hip/hip_runtime.h>

#define HIDDEN  100
#define SEQLEN  65536
#define XTILE   256
#define NT      256   // 4 waves, one per SIMD

typedef float    f32x4 __attribute__((ext_vector_type(4)));
typedef _Float16 h16x2 __attribute__((ext_vector_type(2)));

#define DPP_XOR1 0xB1  // quad_perm [1,0,3,2]: lane <-> lane^1
#define DPP_XOR2 0x4E  // quad_perm [2,3,0,1]: lane <-> lane^2

#if defined(__has_builtin) && __has_builtin(__builtin_amdgcn_rcpf)
#define RCPF(x) __builtin_amdgcn_rcpf(x)
#else
#define RCPF(x) (1.0f / (x))
#endif

#define QSWAP(v, ctrl) __int_as_float(__builtin_amdgcn_mov_dpp(__float_as_int(v), (ctrl), 0xf, 0xf, true))

static __device__ __forceinline__ h16x2 as_h2(unsigned u) {
    union { unsigned u; h16x2 h; } cv; cv.u = u; return cv.h;
}
static __device__ __forceinline__ unsigned pack_f16(float a, float b) {
#if defined(__has_builtin) && __has_builtin(__builtin_amdgcn_cvt_pkrtz)
    auto v = __builtin_amdgcn_cvt_pkrtz(a, b);          // __fp16 ext_vector(2)
    union { decltype(v) h; unsigned u; } cv; cv.h = v;  // bit-cast
    return cv.u;
#else
    union { h16x2 h; unsigned u; } cv;
    cv.h.x = (_Float16)a; cv.h.y = (_Float16)b;
    return cv.u;
#endif
}
static __device__ __forceinline__ float dot2(h16x2 a, h16x2 b, float c) {
#if defined(__has_builtin) && __has_builtin(__builtin_amdgcn_fdot2)
    return __builtin_amdgcn_fdot2(a, b, c, false);
#else
    return __builtin_fmaf((float)a.y, (float)b.y, __builtin_fmaf((float)a.x, (float)b.x, c));
#endif
}

// Lane pair (2j, 2j+1) owns hidden unit j. Each lane: HALF the K-sum (even:
// k<50, odd: k>=50) for ALL FOUR gate rows; DPP-XOR1 merges halves. Then the
// ACTIVATIONS are split across the pair (p0: sigmoid i,f; p1: tanh g, sigmoid o)
// in uniform instruction slots -> gate trans issue halves. Cell update runs on
// p0 lanes (p1's copy is garbage-but-bounded, never read).
// h LDS layout (f16): slots 0..49 = units 0..49 (dw 0..24), dw 25..27 pad;
// slots 56..105 = units 50..99 (dw 28..52), dw 53..55 pad.
__global__ __launch_bounds__(NT) __attribute__((amdgpu_waves_per_eu(1, 1)))
void lstm_seq8(const float* __restrict__ x,      // [SEQ][4]
               const float* __restrict__ W_ih,   // [400][4]
               const float* __restrict__ W_hh,   // [400][100]
               const float* __restrict__ b_ih,   // [400]
               const float* __restrict__ b_hh,   // [400]
               const float* __restrict__ W_lin,  // [1][100]
               const float* __restrict__ b_lin,  // [1]
               float* __restrict__ out)          // [1]
{
    __shared__ __align__(16) unsigned hbuf[2][64];
    __shared__ __align__(16) f32x4 xs[XTILE];
    __shared__ float red[112];

    const int tid = threadIdx.x;
    const int j   = tid >> 1;        // hidden unit (active < 100)
    const int p   = tid & 1;         // K-half / activation role
    const bool active = (j < HIDDEN);
    const int jj  = active ? j : 0;
    const int off = p * 50;          // K offset for this lane

    // ---- per-lane weights: 4 gate half-rows, exactly 25 dwords each (no pad) ----
    h16x2 w[4][25];
    float wx0[4], wx1[4], bz[4];
#pragma unroll
    for (int g = 0; g < 4; ++g) {
        const int row = g * HIDDEN + jj;
        const float* wr = W_hh + row * HIDDEN + off;
#pragma unroll
        for (int q = 0; q < 25; ++q) {
            h16x2 pw; pw.x = (_Float16)wr[2*q]; pw.y = (_Float16)wr[2*q+1];
            w[g][q] = pw;
        }
        const f32x4 wih = reinterpret_cast<const f32x4*>(W_ih)[row];
        wx0[g] = p ? wih.z : wih.x;
        wx1[g] = p ? wih.w : wih.y;
        bz[g]  = p ? 0.f : (b_ih[row] + b_hh[row]);
    }
    const float mm  = p ? 2.0f : 1.0f;   // p1 row-0 act = tanh via 2*sig(2s)-1
    const float mm1 = mm - 1.0f;
    float c = 0.f;                       // valid in p0 lanes only

    if (tid < 64) { hbuf[0][tid] = 0u; hbuf[1][tid] = 0u; }
    __syncthreads();

    auto step = [&](const unsigned* hr, unsigned* hw, const f32x4 xv) {
        const unsigned* hb = hr + p * 28;
        const uint4* h4 = reinterpret_cast<const uint4*>(hb);
        uint4 hv[6];
#pragma unroll
        for (int t = 0; t < 6; ++t) hv[t] = h4[t];   // 6 ds_read_b128
        const unsigned hv6 = hb[24];                 // + 1 ds_read_b32

        const float xe0 = p ? xv.z : xv.x;
        const float xe1 = p ? xv.w : xv.y;
        float a0 = __builtin_fmaf(wx1[0], xe1, __builtin_fmaf(wx0[0], xe0, bz[0]));
        float a1 = __builtin_fmaf(wx1[1], xe1, __builtin_fmaf(wx0[1], xe0, bz[1]));
        float a2 = __builtin_fmaf(wx1[2], xe1, __builtin_fmaf(wx0[2], xe0, bz[2]));
        float a3 = __builtin_fmaf(wx1[3], xe1, __builtin_fmaf(wx0[3], xe0, bz[3]));
#pragma unroll
        for (int t = 0; t < 6; ++t) {
            const h16x2 h0 = as_h2(hv[t].x), h1 = as_h2(hv[t].y);
            const h16x2 h2 = as_h2(hv[t].z), h3 = as_h2(hv[t].w);
            a0 = dot2(w[0][4*t+0], h0, a0); a1 = dot2(w[1][4*t+0], h0, a1);
            a2 = dot2(w[2][4*t+0], h0, a2); a3 = dot2(w[3][4*t+0], h0, a3);
            a0 = dot2(w[0][4*t+1], h1, a0); a1 = dot2(w[1][4*t+1], h1, a1);
            a2 = dot2(w[2][4*t+1], h1, a2); a3 = dot2(w[3][4*t+1], h1, a3);
            a0 = dot2(w[0][4*t+2], h2, a0); a1 = dot2(w[1][4*t+2], h2, a1);
            a2 = dot2(w[2][4*t+2], h2, a2); a3 = dot2(w[3][4*t+2], h2, a3);
            a0 = dot2(w[0][4*t+3], h3, a0); a1 = dot2(w[1][4*t+3], h3, a1);
            a2 = dot2(w[2][4*t+3], h3, a2); a3 = dot2(w[3][4*t+3], h3, a3);
        }
        {
            const h16x2 h6 = as_h2(hv6);             // dword 24 (k 48,49 / 98,99)
            a0 = dot2(w[0][24], h6, a0); a1 = dot2(w[1][24], h6, a1);
            a2 = dot2(w[2][24], h6, a2); a3 = dot2(w[3][24], h6, a3);
        }
        // merge K-halves across the pair (both lanes end with full sums)
        a0 += QSWAP(a0, DPP_XOR1);
        a1 += QSWAP(a1, DPP_XOR1);
        a2 += QSWAP(a2, DPP_XOR1);
        a3 += QSWAP(a3, DPP_XOR1);

        // distributed activations: p0 -> {i=sig(a0), f=sig(a1)},
        //                          p1 -> {g=tanh(a2), o=sig(a3)}
        const float s0 = p ? a2 : a0;
        const float s1 = p ? a3 : a1;
        const float act0 = __builtin_fmaf(mm, RCPF(1.0f + __expf(-s0 * mm)), -mm1);
        const float act1 = RCPF(1.0f + __expf(-s1));
        const float g_ = QSWAP(act0, DPP_XOR1);   // p0 receives g (p1 receives i)
        const float o_ = QSWAP(act1, DPP_XOR1);   // p0 receives o (p1 receives f)

        // cell update: meaningful on p0 lanes (i=act0, f=act1, g=g_, o=o_)
        c = __builtin_fmaf(act1, c, act0 * g_);
        const float th   = __builtin_fmaf(-2.0f, RCPF(1.0f + __expf(2.0f * c)), 1.0f);
        const float hval = o_ * th;

        // pack h pair (units 2m, 2m+1) in lane 4m (a p0 lane) and store one dword
        const float hoth = QSWAP(hval, DPP_XOR2);  // lane 4m <- lane 4m+2's h
        if ((tid & 3) == 0 && active) {
            const int m  = tid >> 2;               // pair index 0..49
            const int dw = (m < 25) ? m : m + 3;   // padded-slot dword
            hw[dw] = pack_f16(hval, hoth);
        }
        __syncthreads();
    };

    const f32x4* x4 = reinterpret_cast<const f32x4*>(x);
    for (int t0 = 0; t0 < SEQLEN; t0 += XTILE) {
        xs[tid] = x4[t0 + tid];
        __syncthreads();
        for (int tt = 0; tt < XTILE; tt += 2) {
            step(hbuf[0], hbuf[1], xs[tt]);      // even: read buf0, write buf1
            step(hbuf[1], hbuf[0], xs[tt + 1]);  // odd:  read buf1, write buf0
        }
    }
    // after an even number of steps the current h is in hbuf[0]

    if (tid < HIDDEN) {
        const int slot = (tid < 50) ? tid : tid + 6;
        const h16x2 hp = as_h2(hbuf[0][slot >> 1]);
        const float hj = (slot & 1) ? (float)hp.y : (float)hp.x;
        red[tid] = hj * W_lin[tid];
    }
    __syncthreads();
    if (tid == 0) {
        float s = b_lin[0];
        for (int q = 0; q < HIDDEN; ++q) s += red[q];
        out[0] = s;
    }
}

extern "C" void kernel_launch(void* const* d_in, const int* in_sizes, int n_in,
                              void* d_out, int out_size, void* d_ws, size_t ws_size,
                              hipStream_t stream) {
    const float* x     = (const float*)d_in[0];
    const float* W_ih  = (const float*)d_in[1];
    const float* W_hh  = (const float*)d_in[2];
    const float* b_ih  = (const float*)d_in[3];
    const float* b_hh  = (const float*)d_in[4];
    const float* W_lin = (const float*)d_in[5];
    const float* b_lin = (const float*)d_in[6];
    float* out = (float*)d_out;

    lstm_seq8<<<dim3(1), dim3(NT), 0, stream>>>(
        x, W_ih, W_hh, b_ih, b_hh, W_lin, b_lin, out);
}